// Round 6
// baseline (901.756 us; speedup 1.0000x reference)
//
#include <hip/hip_runtime.h>
#include <math.h>

typedef unsigned short u16;
typedef unsigned int u32;
#define DEVI __device__ __forceinline__

typedef __attribute__((ext_vector_type(8))) short bf16x8;
typedef __attribute__((ext_vector_type(4))) float f32x4;

// problem constants
constexpr int kB = 2, kC = 96, kD = 32, kH = 64, kW = 64;
constexpr int kS = kD * kH * kW;   // 131072 spatial positions per batch
constexpr int kM = kB * kS;        // 262144 total tokens
constexpr float kScale = 0.17677669529663687f;  // 32^-0.5

DEVI u16 f2bf(float f) {           // fp32 -> bf16 round-to-nearest-even
  u32 x = __float_as_uint(f);
  return (u16)((x + 0x7fffu + ((x >> 16) & 1u)) >> 16);
}
DEVI float bf2f(u16 v) { return __uint_as_float(((u32)v) << 16); }
DEVI u32 pack2(float a, float b) { return (u32)f2bf(a) | ((u32)f2bf(b) << 16); }

// ---------------- transpose (B,C,S) <-> (B,S,C) ----------------
__global__ void k_tin(const float* __restrict__ in, float* __restrict__ out) {
  __shared__ float tile[32][33];
  int s0 = blockIdx.x << 5, c0 = blockIdx.y << 5, b = blockIdx.z;
  int tx = threadIdx.x, ty = threadIdx.y;
#pragma unroll
  for (int q = 0; q < 4; q++)
    tile[ty + q * 8][tx] = in[((size_t)(b * kC + c0 + ty + q * 8)) * kS + s0 + tx];
  __syncthreads();
#pragma unroll
  for (int q = 0; q < 4; q++)
    out[((size_t)(b * kS + s0 + ty + q * 8)) * kC + c0 + tx] = tile[tx][ty + q * 8];
}

__global__ void k_tout(const float* __restrict__ in, float* __restrict__ out) {
  __shared__ float tile[32][33];
  int s0 = blockIdx.x << 5, c0 = blockIdx.y << 5, b = blockIdx.z;
  int tx = threadIdx.x, ty = threadIdx.y;
#pragma unroll
  for (int q = 0; q < 4; q++)
    tile[ty + q * 8][tx] = in[((size_t)(b * kS + s0 + ty + q * 8)) * kC + c0 + tx];
  __syncthreads();
#pragma unroll
  for (int q = 0; q < 4; q++)
    out[((size_t)(b * kC + c0 + ty + q * 8)) * kS + s0 + tx] = tile[tx][ty + q * 8];
}

// ---------------- LayerNorm (one wave per 96-channel row) ----------------
// MODE 1: window-partition output order. MODE 2: window-partition of rolled tensor.
template <int MODE>
__global__ __launch_bounds__(256) void k_ln(const float* __restrict__ x,
                                            const float* __restrict__ g,
                                            const float* __restrict__ bt,
                                            u16* __restrict__ out) {
  int row = (blockIdx.x << 2) + (threadIdx.x >> 6);
  int lane = threadIdx.x & 63;
  int widx = row >> 6, n = row & 63;
  int ww = widx & 15, wh = (widx >> 4) & 15, wd = (widx >> 8) & 7, bb = widx >> 11;
  int lw = n & 3, lh = (n >> 2) & 3, ld = n >> 4;
  int d = wd * 4 + ld, h = wh * 4 + lh, w = ww * 4 + lw;
  if (MODE == 2) { d = (d + 2) & 31; h = (h + 2) & 63; w = (w + 2) & 63; }
  int src = ((bb * kD + d) * kH + h) * kW + w;
  const float* xr = x + (size_t)src * kC;
  float a0 = xr[lane];
  float a1 = (lane < 32) ? xr[64 + lane] : 0.f;
  float sum = a0 + a1;
#pragma unroll
  for (int m = 32; m; m >>= 1) sum += __shfl_xor(sum, m);
  float mean = sum * (1.f / 96.f);
  float d0 = a0 - mean, d1 = (lane < 32) ? a1 - mean : 0.f;
  float vs = d0 * d0 + d1 * d1;
#pragma unroll
  for (int m = 32; m; m >>= 1) vs += __shfl_xor(vs, m);
  float rstd = rsqrtf(vs * (1.f / 96.f) + 1e-5f);
  u16* orow = out + (size_t)row * kC;
  orow[lane] = f2bf(d0 * rstd * g[lane] + bt[lane]);
  if (lane < 32) orow[64 + lane] = f2bf(d1 * rstd * g[64 + lane] + bt[64 + lane]);
}

// ---------------- MFMA GEMM: out[r][j] = sum_k X[r][k]*W[j][k] + b[j] -------
// Block = 128 rows x 96 cols, 4 waves (each 32 rows x 96 cols, 2x6 frags).
// A-fragments load DIRECTLY from global (no X LDS staging -> 19.5 KB LDS,
// 4 blocks/CU). W fp32 staged to LDS as bf16.
// EPI 1: GELU -> bf16. EPI 2: fp32 += into oadd. EPI 3: resid+LN fused.
// GATHER 1: X row = window-partition source of natural row r.
template <int KTOT, int EPI, int GATHER>
__global__ __launch_bounds__(256, 4) void k_mm(const u16* __restrict__ X,
                                               const float* __restrict__ Wm,
                                               const float* __restrict__ bias,
                                               u16* __restrict__ obf,
                                               float* __restrict__ oadd,
                                               const float* __restrict__ lng,
                                               const float* __restrict__ lnb,
                                               int njtot, int shifted) {
  __shared__ __align__(16) u16 Ws[96][104];
  int tid = threadIdx.x;
  int wv = tid >> 6, lane = tid & 63;
  int llo = lane & 15, lhi = lane >> 4;
  int r0 = blockIdx.x << 7;
  int j0 = blockIdx.y * 96;

  // per-lane A row addresses (gathered once)
  size_t arow[2];
#pragma unroll
  for (int i = 0; i < 2; i++) {
    int r = r0 + wv * 32 + i * 16 + llo, rsrc;
    if (GATHER) {
      int w = r & 63, h = (r >> 6) & 63, d = (r >> 12) & 31, bb = r >> 17;
      if (shifted) { d = (d + 30) & 31; h = (h + 62) & 63; w = (w + 62) & 63; }
      int widx = ((bb * 8 + (d >> 2)) * 16 + (h >> 2)) * 16 + (w >> 2);
      rsrc = (widx << 6) + ((d & 3) << 4) + ((h & 3) << 2) + (w & 3);
    } else {
      rsrc = r;
    }
    arow[i] = (size_t)rsrc * KTOT;
  }

  f32x4 acc[2][6];
#pragma unroll
  for (int i = 0; i < 2; i++)
#pragma unroll
    for (int j = 0; j < 6; j++) acc[i][j] = (f32x4){0.f, 0.f, 0.f, 0.f};

  for (int kc = 0; kc < KTOT; kc += 96) {
    // issue A loads first so they fly under W staging
    bf16x8 a[2][3];
#pragma unroll
    for (int i = 0; i < 2; i++)
#pragma unroll
      for (int ks = 0; ks < 3; ks++)
        a[i][ks] = *(const bf16x8*)(X + arow[i] + kc + ks * 32 + lhi * 8);
    if (kc) __syncthreads();
    for (int s = tid; s < 96 * 12; s += 256) {
      int row = s / 12, c8 = s - row * 12;
      const float* src = Wm + (size_t)(j0 + row) * KTOT + kc + c8 * 8;
      float4 w0 = *(const float4*)src, w1 = *(const float4*)(src + 4);
      uint4 pk = {pack2(w0.x, w0.y), pack2(w0.z, w0.w),
                  pack2(w1.x, w1.y), pack2(w1.z, w1.w)};
      *(uint4*)&Ws[row][c8 * 8] = pk;
    }
    __syncthreads();
#pragma unroll
    for (int ks = 0; ks < 3; ks++) {
      bf16x8 b[6];
#pragma unroll
      for (int j = 0; j < 6; j++)
        b[j] = *(const bf16x8*)&Ws[j * 16 + llo][ks * 32 + lhi * 8];
#pragma unroll
      for (int i = 0; i < 2; i++)
#pragma unroll
        for (int j = 0; j < 6; j++)
          acc[i][j] = __builtin_amdgcn_mfma_f32_16x16x32_bf16(a[i][ks], b[j], acc[i][j], 0, 0, 0);
    }
  }

  if (EPI == 3) {
    // fused residual + LayerNorm epilogue (j0 == 0, full 96 cols per block)
    float bj[6], gj[6], betaj[6];
#pragma unroll
    for (int j = 0; j < 6; j++) {
      int col = j * 16 + llo;
      bj[j] = bias[col]; gj[j] = lng[col]; betaj[j] = lnb[col];
    }
#pragma unroll
    for (int i = 0; i < 2; i++) {
#pragma unroll
      for (int rg = 0; rg < 4; rg++) {
        int row = r0 + wv * 32 + i * 16 + lhi * 4 + rg;
        float vv[6], sum = 0.f;
#pragma unroll
        for (int j = 0; j < 6; j++) {
          vv[j] = acc[i][j][rg] + bj[j] + oadd[(size_t)row * 96 + j * 16 + llo];
          sum += vv[j];
        }
#pragma unroll
        for (int m = 1; m <= 8; m <<= 1) sum += __shfl_xor(sum, m);
        float mean = sum * (1.f / 96.f);
        float vs = 0.f;
#pragma unroll
        for (int j = 0; j < 6; j++) { float dd = vv[j] - mean; vs += dd * dd; }
#pragma unroll
        for (int m = 1; m <= 8; m <<= 1) vs += __shfl_xor(vs, m);
        float rstd = rsqrtf(vs * (1.f / 96.f) + 1e-5f);
#pragma unroll
        for (int j = 0; j < 6; j++) {
          int col = j * 16 + llo;
          oadd[(size_t)row * 96 + col] = vv[j];
          obf[(size_t)row * 96 + col] = f2bf((vv[j] - mean) * rstd * gj[j] + betaj[j]);
        }
      }
    }
  } else {
#pragma unroll
    for (int i = 0; i < 2; i++) {
      int rbase = r0 + wv * 32 + i * 16 + lhi * 4;
#pragma unroll
      for (int j = 0; j < 6; j++) {
        int col = j0 + j * 16 + llo;
        float bv = bias[col];
#pragma unroll
        for (int rg = 0; rg < 4; rg++) {
          float v = acc[i][j][rg] + bv;
          int row = rbase + rg;
          if (EPI == 1) {
            obf[(size_t)row * njtot + col] =
                f2bf(0.5f * v * (1.f + erff(v * 0.70710678118654752f)));
          } else {
            oadd[(size_t)row * 96 + col] += v;
          }
        }
      }
    }
  }
}

// ---------------- fused QKV-GEMM + windowed attention (16 waves) -----------
// One block = 2 windows (128 rows), 1024 threads. GEMM: wave = 16 rows x 48
// cols, A-frags direct from global. Q/K -> LDS row-major; V -> LDS transposed.
// Attention: 12 units (pair,head,qhalf) on waves 0..11; P overlays dead QK.
__global__ __launch_bounds__(1024, 4) void k_qa(const u16* __restrict__ X,
                                                const float* __restrict__ Wq,
                                                const float* __restrict__ bq,
                                                const float* __restrict__ rpb,
                                                u16* __restrict__ out, int shifted) {
  __shared__ __align__(16) char arena[90656];
  u16* QK = (u16*)arena;                 // [128][200]: cols 0..95 Q, 96..191 K
  u16* VT = (u16*)(arena + 51200);       // [pair*3+head][32 d][40]: V^T
  u16* Ws = (u16*)(arena + 66560);       // [96][104]
  float* RP = (float*)(arena + 86528);   // [3][343]

  int tid = threadIdx.x, wv = tid >> 6, lane = tid & 63;
  int llo = lane & 15, lhi = lane >> 4;
  int r0 = blockIdx.x << 7;
  int rowb = (wv >> 1) * 16;             // GEMM row base
  int colb = (wv & 1) * 48;              // GEMM col base

  // rel-pos bias table (region independent of GEMM buffers)
  for (int t = tid; t < 1029; t += 1024) {
    int head = t / 343, idx = t - head * 343;
    RP[t] = rpb[idx * 3 + head];
  }

  // A-fragments for this lane's 16 GEMM rows (shared across Q/K/V chunks)
  const u16* xrow = X + (size_t)(r0 + rowb + llo) * 96;
  bf16x8 a[3];
#pragma unroll
  for (int ks = 0; ks < 3; ks++) a[ks] = *(const bf16x8*)(xrow + ks * 32 + lhi * 8);

  for (int c = 0; c < 3; c++) {
    if (c) __syncthreads();
    for (int s = tid; s < 96 * 12; s += 1024) {
      int row = s / 12, c8 = s - row * 12;
      const float* src = Wq + (size_t)(c * 96 + row) * 96 + c8 * 8;
      float4 w0 = *(const float4*)src, w1 = *(const float4*)(src + 4);
      uint4 pk = {pack2(w0.x, w0.y), pack2(w0.z, w0.w),
                  pack2(w1.x, w1.y), pack2(w1.z, w1.w)};
      *(uint4*)&Ws[row * 104 + c8 * 8] = pk;
    }
    __syncthreads();
    f32x4 acc[3];
#pragma unroll
    for (int j = 0; j < 3; j++) acc[j] = (f32x4){0.f, 0.f, 0.f, 0.f};
#pragma unroll
    for (int ks = 0; ks < 3; ks++) {
#pragma unroll
      for (int j = 0; j < 3; j++) {
        bf16x8 b = *(const bf16x8*)&Ws[(colb + j * 16 + llo) * 104 + ks * 32 + lhi * 8];
        acc[j] = __builtin_amdgcn_mfma_f32_16x16x32_bf16(a[ks], b, acc[j], 0, 0, 0);
      }
    }
    if (c < 2) {  // Q / K -> QK row-major
#pragma unroll
      for (int j = 0; j < 3; j++) {
        int col = colb + j * 16 + llo;
        float bb_ = bq[c * 96 + col];
#pragma unroll
        for (int rg = 0; rg < 4; rg++)
          QK[(rowb + lhi * 4 + rg) * 200 + c * 96 + col] = f2bf(acc[j][rg] + bb_);
      }
    } else {      // V -> VT transposed per (pair, head)
#pragma unroll
      for (int j = 0; j < 3; j++) {
        int dcol = colb + j * 16 + llo;
        float bb_ = bq[192 + dcol];
        int head = dcol >> 5, d = dcol & 31;
#pragma unroll
        for (int rg = 0; rg < 4; rg++) {
          int row = rowb + lhi * 4 + rg;
          VT[(((row >> 6) * 3 + head) * 32 + d) * 40 + (row & 63)] = f2bf(acc[j][rg] + bb_);
        }
      }
    }
  }
  __syncthreads();

  // attention: 12 units = (pair, head, q-half); waves 12..15 idle
  int u = wv;
  bool active = (u < 12);
  int pair = u / 6, rem = u - pair * 6, head = rem >> 1, qh = rem & 1;
  int widx = (blockIdx.x << 1) + pair;
  int ww = widx & 15, wh = (widx >> 4) & 15, wd = (widx >> 8) & 7;
  const float* rp = RP + head * 343;
  const u16* qkw = QK + pair * 64 * 200;
  u16* plw = QK + u * 2112;              // P overlay on dead QK (32 x stride 66)

  f32x4 s[2][4];
  bf16x8 bv[2][2];
  if (active) {
    bf16x8 aq[2], bk[4];
#pragma unroll
    for (int qt2 = 0; qt2 < 2; qt2++)
      aq[qt2] = *(const bf16x8*)&qkw[(qh * 32 + qt2 * 16 + llo) * 200 + head * 32 + lhi * 8];
#pragma unroll
    for (int kt = 0; kt < 4; kt++)
      bk[kt] = *(const bf16x8*)&qkw[(kt * 16 + llo) * 200 + 96 + head * 32 + lhi * 8];
    // V fragments (VT region is not overlaid; load now to hide latency)
    const u16* vtb = VT + (pair * 3 + head) * 32 * 40;
#pragma unroll
    for (int jt = 0; jt < 2; jt++)
#pragma unroll
      for (int ks = 0; ks < 2; ks++)
        bv[jt][ks] = *(const bf16x8*)&vtb[(jt * 16 + llo) * 40 + ks * 32 + lhi * 8];

#pragma unroll
    for (int qt2 = 0; qt2 < 2; qt2++)
#pragma unroll
      for (int kt = 0; kt < 4; kt++)
        s[qt2][kt] = __builtin_amdgcn_mfma_f32_16x16x32_bf16(
            aq[qt2], bk[kt], (f32x4){0.f, 0.f, 0.f, 0.f}, 0, 0, 0);

    int jh = llo >> 2, jw = llo & 3;
    int mi_h = (wh == 15) ? (1 + (lhi >= 2)) : 0;
    int mj_hw = ((wh == 15) ? (1 + (jh >= 2)) : 0) * 3 +
                ((ww == 15) ? (1 + (jw >= 2)) : 0);
#pragma unroll
    for (int qt2 = 0; qt2 < 2; qt2++) {
      int qt = qh * 2 + qt2;
#pragma unroll
      for (int kt = 0; kt < 4; kt++) {
        const float* rb = &rp[(qt - kt + 3) * 49 + (lhi - jh + 3) * 7 + (3 - jw)];
#pragma unroll
        for (int e = 0; e < 4; e++) {
          float val = fmaf(s[qt2][kt][e], kScale, rb[e]);
          if (shifted) {
            int ci = ((wd == 7) ? (1 + (qt >= 2)) : 0) * 9 + mi_h * 3 +
                     ((ww == 15) ? (1 + (e >= 2)) : 0);
            int cj = ((wd == 7) ? (1 + (kt >= 2)) : 0) * 9 + mj_hw;
            if (ci != cj) val -= 100.f;
          }
          s[qt2][kt][e] = val;
        }
      }
    }
    // softmax per row (qt2, e): local max/sum over kt, butterfly over llo
#pragma unroll
    for (int qt2 = 0; qt2 < 2; qt2++) {
      f32x4 m;
#pragma unroll
      for (int e = 0; e < 4; e++)
        m[e] = fmaxf(fmaxf(s[qt2][0][e], s[qt2][1][e]), fmaxf(s[qt2][2][e], s[qt2][3][e]));
#pragma unroll
      for (int msk = 1; msk <= 8; msk <<= 1)
#pragma unroll
        for (int e = 0; e < 4; e++) m[e] = fmaxf(m[e], __shfl_xor(m[e], msk));
      f32x4 sum = (f32x4){0.f, 0.f, 0.f, 0.f};
#pragma unroll
      for (int kt = 0; kt < 4; kt++)
#pragma unroll
        for (int e = 0; e < 4; e++) {
          float p = __expf(s[qt2][kt][e] - m[e]);
          s[qt2][kt][e] = p;
          sum[e] += p;
        }
#pragma unroll
      for (int msk = 1; msk <= 8; msk <<= 1)
#pragma unroll
        for (int e = 0; e < 4; e++) sum[e] += __shfl_xor(sum[e], msk);
#pragma unroll
      for (int e = 0; e < 4; e++) sum[e] = 1.f / sum[e];
#pragma unroll
      for (int kt = 0; kt < 4; kt++)
#pragma unroll
        for (int e = 0; e < 4; e++) s[qt2][kt][e] *= sum[e];
    }
  }
  __syncthreads();  // all QK reads complete -> safe to overlay P
  if (active) {
#pragma unroll
    for (int qt2 = 0; qt2 < 2; qt2++)
#pragma unroll
      for (int kt = 0; kt < 4; kt++)
#pragma unroll
        for (int e = 0; e < 4; e++)
          plw[(qt2 * 16 + lhi * 4 + e) * 66 + kt * 16 + llo] = f2bf(s[qt2][kt][e]);
  }
  __syncthreads();
  if (active) {
    f32x4 o[2][2];
#pragma unroll
    for (int qt2 = 0; qt2 < 2; qt2++) {
      o[qt2][0] = (f32x4){0.f, 0.f, 0.f, 0.f};
      o[qt2][1] = (f32x4){0.f, 0.f, 0.f, 0.f};
#pragma unroll
      for (int ks = 0; ks < 2; ks++) {
        bf16x8 pa = *(const bf16x8*)&plw[(qt2 * 16 + llo) * 66 + ks * 32 + lhi * 8];
        o[qt2][0] = __builtin_amdgcn_mfma_f32_16x16x32_bf16(pa, bv[0][ks], o[qt2][0], 0, 0, 0);
        o[qt2][1] = __builtin_amdgcn_mfma_f32_16x16x32_bf16(pa, bv[1][ks], o[qt2][1], 0, 0, 0);
      }
    }
    u16* ob = out + (size_t)widx * 64 * 96 + head * 32;
#pragma unroll
    for (int qt2 = 0; qt2 < 2; qt2++)
#pragma unroll
      for (int jt = 0; jt < 2; jt++)
#pragma unroll
        for (int e = 0; e < 4; e++)
          ob[(size_t)(qh * 32 + qt2 * 16 + lhi * 4 + e) * 96 + jt * 16 + llo] =
              f2bf(o[qt2][jt][e]);
  }
}

// ---------------- launcher ----------------
extern "C" void kernel_launch(void* const* d_in, const int* in_sizes, int n_in,
                              void* d_out, int out_size, void* d_ws, size_t ws_size,
                              hipStream_t stream) {
  const float* x_in = (const float*)d_in[0];
  const float* n1g = (const float*)d_in[1];
  const float* n1b = (const float*)d_in[2];
  const float* qkvw = (const float*)d_in[3];
  const float* qkvb = (const float*)d_in[4];
  const float* rpb = (const float*)d_in[5];
  const float* projw = (const float*)d_in[6];
  const float* projb = (const float*)d_in[7];
  const float* n2g = (const float*)d_in[8];
  const float* n2b = (const float*)d_in[9];
  const float* fc1w = (const float*)d_in[10];
  const float* fc1b = (const float*)d_in[11];
  const float* fc2w = (const float*)d_in[12];
  const float* fc2b = (const float*)d_in[13];
  float* outp = (float*)d_out;

  // workspace: fp32 master x (100.7 MB) | bf16 small buf (50.3 MB) | bf16 big buf (201.3 MB)
  char* ws = (char*)d_ws;
  float* bx = (float*)ws;
  u16* ba = (u16*)(ws + 100663296);   // LN outs (window order)
  u16* bb = (u16*)(ws + 150994944);   // attn-out / mlp hidden

  k_tin<<<dim3(kS / 32, 3, kB), dim3(32, 8), 0, stream>>>(x_in, bx);

  for (int blk = 0; blk < 2; blk++) {
    int sh = blk;  // block 1 is shifted
    if (blk == 0)
      k_ln<1><<<kM / 4, 256, 0, stream>>>(bx, n1g, n1b, ba);
    else
      k_ln<2><<<kM / 4, 256, 0, stream>>>(bx, n1g + 96, n1b + 96, ba);
    k_qa<<<kM / 128, 1024, 0, stream>>>(ba, qkvw + blk * 288 * 96, qkvb + blk * 288,
                                        rpb + blk * 343 * 3, bb, sh);
    // proj + residual + LN2 fused
    k_mm<96, 3, 1><<<dim3(kM / 128, 1), 256, 0, stream>>>(
        bb, projw + blk * 96 * 96, projb + blk * 96, ba, bx,
        n2g + blk * 96, n2b + blk * 96, 96, sh);
    k_mm<96, 1, 0><<<dim3(kM / 128, 4), 256, 0, stream>>>(
        ba, fc1w + blk * 384 * 96, fc1b + blk * 384, bb, nullptr, nullptr, nullptr, 384, 0);
    k_mm<384, 2, 0><<<dim3(kM / 128, 1), 256, 0, stream>>>(
        bb, fc2w + blk * 96 * 384, fc2b + blk * 96, nullptr, bx, nullptr, nullptr, 96, 0);
  }

  k_tout<<<dim3(kS / 32, 3, kB), dim3(32, 8), 0, stream>>>(bx, outp);
}